// Round 9
// baseline (76.053 us; speedup 1.0000x reference)
//
#include <hip/hip_runtime.h>
#include <hip/hip_fp16.h>
#include <math.h>

// Problem constants (match reference exactly)
#define BROWS 1024
#define NPTS  32768
#define MPTS  16384          // complex FFT size via real-packing trick
#define NTHR  512            // 8 waves
#define MIN_IDX 1092         // argmin |f - 40/60|, f[k]=k*10/16384 (exact fp32 grid)
#define MAX_IDX 6827         // argmin |f - 250/60|
#define DENOMF  5732.0f      // MAX_IDX - MIN_IDX - 3

// Four-step FFT: 16384 = 128x128. n = 128*n1 + n2, k = k1 + 128*k2.
//   step1: Y[k1][n2] = sum_n1 F[k1][n1] Z[n1][n2]   (F = 128-pt DFT matrix)
//   twiddle: Bm = Y * W_16384^(k1*n2)
//   step3: X[k1+128*k2] = sum_n2 Bm[k1][n2] F[n2][k2]   (F symmetric)
// Both steps are 128^3 complex matmuls on mfma_f32_16x16x32_f16.

#define LD 140   // LDS row stride in half2 words: 16B-aligned frag bases, low bank aliasing

typedef _Float16 h8 __attribute__((ext_vector_type(8)));
typedef float    f4 __attribute__((ext_vector_type(4)));

#define MFMA(a, b, c) __builtin_amdgcn_mfma_f32_16x16x32_f16((a), (b), (c), 0, 0, 0)

// MFMA fragment lane layout (gfx950, 16x16x32):
//   A: lane l holds A[row = l&15][k = 8*(l>>4) + j], j=0..7  (b128-contiguous k)
//   B: lane l holds B[k = 8*(l>>4) + j][col = l&15]
//   C/D: lane l, reg v holds D[row = 4*(l>>4)+v][col = l&15]   (m89-verified)

struct Frag { h8 r, i; };

// Load a complex fragment from an LDS half2 matrix: 8 consecutive half2
// (two ds_read_b128), de-interleave into real/imag h8 vectors.
__device__ inline Frag load_frag(const __half2* __restrict__ base) {
    const float4* p = reinterpret_cast<const float4*>(base);
    union { float4 f; _Float16 h[8]; } a, b;
    a.f = p[0]; b.f = p[1];
    Frag fr;
    fr.r = (h8){a.h[0], a.h[2], a.h[4], a.h[6], b.h[0], b.h[2], b.h[4], b.h[6]};
    fr.i = (h8){a.h[1], a.h[3], a.h[5], a.h[7], b.h[1], b.h[3], b.h[5], b.h[7]};
    return fr;
}

// F-matrix fragment on the fly: F[row][k] = e^{-2pi i (row*k)/128}, k = kbase+j.
// Integer reduction (row*k)&127 keeps __sincosf args in [-2pi, 0].
__device__ inline void make_F(int row, int kbase, h8& fr, h8& fi) {
    #pragma unroll
    for (int j = 0; j < 8; ++j) {
        int e = (row * (kbase + j)) & 127;
        float ang = -0.04908738521234052f * (float)e;   // -2pi/128
        float s, c;
        __sincosf(ang, &s, &c);
        fr[j] = (_Float16)c;
        fi[j] = (_Float16)s;
    }
}

// |X[k]|^2 (ortho) from the complex-FFT matrix C[k2][k1] (direct indexing).
__device__ inline float bin_power2(const __half2* __restrict__ C, int k) {
    float2 a  = __half22float2(C[(k >> 7) * LD + (k & 127)]);
    int p = MPTS - k;
    float2 bz = __half22float2(C[(p >> 7) * LD + (p & 127)]);
    float bx = bz.x, by = -bz.y;                  // conj(Z[M-k])
    float ex = 0.5f * (a.x + bx), ey = 0.5f * (a.y + by);   // Xe[k]
    float dx = a.x - bx,          dy = a.y - by;
    float ox = 0.5f * dy,         oy = -0.5f * dx;          // Xo[k]
    float ang = (-6.283185307179586f / (float)NPTS) * (float)k;
    float c, sn;
    __sincosf(ang, &sn, &c);
    float Xx = ex + ox * c - oy * sn;
    float Xy = ey + ox * sn + oy * c;
    return (Xx * Xx + Xy * Xy) * (1.0f / (float)NPTS);      // ortho: |X|^2 / N
}

__global__ __launch_bounds__(NTHR, 2) void snr_row_kernel(
        const float* __restrict__ outs,
        const float* __restrict__ targets,
        float* __restrict__ row_loss) {
    // bufA: Zt[n2][n1] for step1, then Ct[k2][k1] after step3 (overlay).
    // bufB: Bm[k1][n2] (twiddled intermediate).
    __shared__ __align__(16) __half2 bufA[128 * LD];
    __shared__ __align__(16) __half2 bufB[128 * LD];
    __shared__ float red[NTHR / 64];

    const int b    = blockIdx.x;
    const int tid  = threadIdx.x;
    const int lane = tid & 63;
    const int w    = tid >> 6;          // wave id 0..7 = panel id
    const int r15  = lane & 15;
    const int g    = lane >> 4;
    const float2* row = reinterpret_cast<const float2*>(outs + (size_t)b * NPTS);

    // ---- Stage: Zt[n2][n1] = z[128*n1 + n2] = (x[2m], x[2m+1]) transposed
    #pragma unroll
    for (int it = 0; it < MPTS / NTHR; ++it) {
        int m = tid + it * NTHR;
        float2 v = row[m];
        bufA[(m & 127) * LD + (m >> 7)] = __floats2half2_rn(v.x, v.y);
    }
    __syncthreads();

    // ---- F fragments for this wave's panel: F[16w+r15][32kc+8g+j].
    // Identical values serve step1's A-side (row = k1) and step3's B-side
    // (col = k2, F symmetric) because this wave owns panel w in both.
    h8 fr[4], fi[4], fin[4];
    #pragma unroll
    for (int kc = 0; kc < 4; ++kc) {
        make_F(16 * w + r15, 32 * kc + 8 * g, fr[kc], fi[kc]);
        fin[kc] = -fi[kc];
    }

    // ---- Step 1: Y(panel w) = F * Z; twiddle; write Bm[k1][n2]
    #pragma unroll
    for (int n0 = 0; n0 < 8; ++n0) {
        f4 accr = {0.f, 0.f, 0.f, 0.f}, acci = {0.f, 0.f, 0.f, 0.f};
        #pragma unroll
        for (int kc = 0; kc < 4; ++kc) {
            Frag z = load_frag(&bufA[(16 * n0 + r15) * LD + 32 * kc + 8 * g]);
            accr = MFMA(fr[kc],  z.r, accr);    // Yr = Fr Zr - Fi Zi
            accr = MFMA(fin[kc], z.i, accr);
            acci = MFMA(fr[kc],  z.i, acci);    // Yi = Fr Zi + Fi Zr
            acci = MFMA(fi[kc],  z.r, acci);
        }
        #pragma unroll
        for (int v = 0; v < 4; ++v) {
            int k1 = 16 * w + 4 * g + v;
            int n2 = 16 * n0 + r15;
            int e  = (k1 * n2) & 16383;
            float ang = -3.834951969714103e-4f * (float)e;  // -2pi/16384
            float s, c;
            __sincosf(ang, &s, &c);
            float br = accr[v] * c - acci[v] * s;
            float bi = accr[v] * s + acci[v] * c;
            bufB[k1 * LD + n2] = __floats2half2_rn(br, bi);
        }
    }
    __syncthreads();

    // ---- Step 3: X = Bm * F (col panel w); write Ct[k2][k1] over bufA
    #pragma unroll
    for (int m0 = 0; m0 < 8; ++m0) {
        f4 accr = {0.f, 0.f, 0.f, 0.f}, acci = {0.f, 0.f, 0.f, 0.f};
        #pragma unroll
        for (int kc = 0; kc < 4; ++kc) {
            Frag a = load_frag(&bufB[(16 * m0 + r15) * LD + 32 * kc + 8 * g]);
            h8 ain = -a.i;
            accr = MFMA(a.r, fr[kc], accr);     // Xr = Br Fr - Bi Fi
            accr = MFMA(ain, fi[kc], accr);
            acci = MFMA(a.r, fi[kc], acci);     // Xi = Br Fi + Bi Fr
            acci = MFMA(a.i, fr[kc], acci);
        }
        #pragma unroll
        for (int v = 0; v < 4; ++v) {
            int k1 = 16 * m0 + 4 * g + v;
            int k2 = 16 * w + r15;
            bufA[k2 * LD + k1] = __floats2half2_rn(accr[v], acci[v]);
        }
    }
    __syncthreads();

    // ---- Band power sum [MIN_IDX, MAX_IDX): consecutive-word reads, no
    // bit-reversal (direct k indexing), conflict-free.
    float local = 0.0f;
    for (int k = MIN_IDX + tid; k < MAX_IDX; k += NTHR)
        local += bin_power2(bufA, k);

    for (int off = 32; off; off >>= 1) local += __shfl_down(local, off);
    if ((tid & 63) == 0) red[w] = local;
    __syncthreads();

    if (tid == 0) {
        float S = 0.0f;
        #pragma unroll
        for (int q = 0; q < NTHR / 64; ++q) S += red[q];

        // ref_idx: argmin_k |f[k]-t|, f[k] = k*(10/16384) exact in fp32.
        float tgt = targets[b];
        double kd = (double)tgt * (16384.0 / 10.0);
        int k0 = (int)kd;                       // t>0 so trunc == floor
        const float stepf = 10.0f / 16384.0f;   // exactly representable
        float f0 = (float)k0 * stepf;           // exact products (<=24b)
        float f1 = (float)(k0 + 1) * stepf;
        float d0 = fabsf(f0 - tgt);
        float d1 = fabsf(f1 - tgt);
        int rr = (d0 <= d1) ? k0 : (k0 + 1);

        float pm1 = bin_power2(bufA, rr - 1);
        float p0  = bin_power2(bufA, rr);
        float pp1 = bin_power2(bufA, rr + 1);
        float other_avg = (S - pm1 - p0 - pp1) * (1.0f / DENOMF);
        row_loss[b] = -10.0f * log10f(p0 / other_avg);
    }
}

__global__ __launch_bounds__(256) void snr_reduce_kernel(
        const float* __restrict__ row_loss, float* __restrict__ out) {
    __shared__ float red[4];
    float s = 0.0f;
    for (int i = threadIdx.x; i < BROWS; i += 256) s += row_loss[i];
    for (int off = 32; off; off >>= 1) s += __shfl_down(s, off);
    if ((threadIdx.x & 63) == 0) red[threadIdx.x >> 6] = s;
    __syncthreads();
    if (threadIdx.x == 0)
        out[0] = (red[0] + red[1] + red[2] + red[3]) * (1.0f / (float)BROWS);
}

extern "C" void kernel_launch(void* const* d_in, const int* in_sizes, int n_in,
                              void* d_out, int out_size, void* d_ws, size_t ws_size,
                              hipStream_t stream) {
    const float* outs    = (const float*)d_in[0];
    const float* targets = (const float*)d_in[1];
    float* ws  = (float*)d_ws;    // 1024 per-row losses
    float* out = (float*)d_out;

    snr_row_kernel<<<BROWS, NTHR, 0, stream>>>(outs, targets, ws);
    snr_reduce_kernel<<<1, 256, 0, stream>>>(ws, out);
}

// Round 10
// 60.399 us; speedup vs baseline: 1.2592x; 1.2592x over previous
//
#include <hip/hip_runtime.h>
#include <hip/hip_fp16.h>
#include <math.h>

// Problem constants (match reference exactly)
#define BROWS 1024
#define NPTS  32768
#define MPTS  16384          // complex FFT size via real-packing trick
#define NTHR  512            // 8 waves
#define MIN_IDX 1092         // argmin |f - 40/60|, f[k]=k*10/16384 (exact fp32 grid)
#define MAX_IDX 6827         // argmin |f - 250/60|
#define DENOMF  5732.0f      // MAX_IDX - MIN_IDX - 3

// Four-step FFT: 16384 = 128x128. n = 128*n1 + n2, k = k1 + 128*k2.
//   step1: Y[k1][n2] = sum_n1 F[k1][n1] Z[n1][n2]   (F = 128-pt DFT matrix)
//   twiddle: Bm = Y * W_16384^(k1*n2)
//   step3: X[k1+128*k2] = sum_n2 Bm[k1][n2] F[n2][k2]   (F symmetric)
// SINGLE LDS buffer: Zt -> (reg-held panel) -> Bm overlay -> (reg panel) -> Ct.
// Each wave writes only its own 16-row panel, always after a barrier that
// ends all reads of the previous contents -> no inter-wave hazard.

#define LD 140   // LDS row stride in half2 words: 16B-aligned frag bases

typedef _Float16 h8 __attribute__((ext_vector_type(8)));
typedef float    f4 __attribute__((ext_vector_type(4)));

#define MFMA(a, b, c) __builtin_amdgcn_mfma_f32_16x16x32_f16((a), (b), (c), 0, 0, 0)

// MFMA fragment lane layout (gfx950, 16x16x32, verified R8 absmax=0):
//   A: lane l holds A[row = l&15][k = 8*(l>>4) + j], j=0..7
//   B: lane l holds B[k = 8*(l>>4) + j][col = l&15]
//   C/D: lane l, reg v holds D[row = 4*(l>>4)+v][col = l&15]

struct Frag { h8 r, i; };

// Load a complex fragment from an LDS half2 matrix: 8 consecutive half2
// (two ds_read_b128), de-interleave into real/imag h8 vectors.
__device__ inline Frag load_frag(const __half2* __restrict__ base) {
    const float4* p = reinterpret_cast<const float4*>(base);
    union { float4 f; _Float16 h[8]; } a, b;
    a.f = p[0]; b.f = p[1];
    Frag fr;
    fr.r = (h8){a.h[0], a.h[2], a.h[4], a.h[6], b.h[0], b.h[2], b.h[4], b.h[6]};
    fr.i = (h8){a.h[1], a.h[3], a.h[5], a.h[7], b.h[1], b.h[3], b.h[5], b.h[7]};
    return fr;
}

// F-matrix fragment on the fly: F[row][k] = e^{-2pi i (row*k)/128}, k = kbase+j.
// Integer reduction (row*k)&127 keeps __sincosf args in [-2pi, 0].
__device__ inline void make_F(int row, int kbase, h8& fr, h8& fi) {
    #pragma unroll
    for (int j = 0; j < 8; ++j) {
        int e = (row * (kbase + j)) & 127;
        float ang = -0.04908738521234052f * (float)e;   // -2pi/128
        float s, c;
        __sincosf(ang, &s, &c);
        fr[j] = (_Float16)c;
        fi[j] = (_Float16)s;
    }
}

// |X[k]|^2 (ortho) from the complex-FFT matrix C[k2][k1] (direct indexing).
__device__ inline float bin_power2(const __half2* __restrict__ C, int k) {
    float2 a  = __half22float2(C[(k >> 7) * LD + (k & 127)]);
    int p = MPTS - k;
    float2 bz = __half22float2(C[(p >> 7) * LD + (p & 127)]);
    float bx = bz.x, by = -bz.y;                  // conj(Z[M-k])
    float ex = 0.5f * (a.x + bx), ey = 0.5f * (a.y + by);   // Xe[k]
    float dx = a.x - bx,          dy = a.y - by;
    float ox = 0.5f * dy,         oy = -0.5f * dx;          // Xo[k]
    float ang = (-6.283185307179586f / (float)NPTS) * (float)k;
    float c, sn;
    __sincosf(ang, &sn, &c);
    float Xx = ex + ox * c - oy * sn;
    float Xy = ey + ox * sn + oy * c;
    return (Xx * Xx + Xy * Xy) * (1.0f / (float)NPTS);      // ortho: |X|^2 / N
}

// (512, 4): VGPR target 128 = 4 waves/SIMD so TWO 70 KiB blocks co-reside.
// Body pressure ~100-115 (packed panel 32 + F frags 32 + transients).
// Tripwires for silent spill: FETCH_SIZE >> 66 MB or WRITE_SIZE >> 32 KB.
__global__ __launch_bounds__(NTHR, 4) void snr_row_kernel(
        const float* __restrict__ outs,
        const float* __restrict__ targets,
        float* __restrict__ row_loss) {
    __shared__ __align__(16) __half2 bufA[128 * LD];    // 70 KiB, single buffer
    __shared__ float red[NTHR / 64];

    const int b    = blockIdx.x;
    const int tid  = threadIdx.x;
    const int lane = tid & 63;
    const int w    = tid >> 6;          // wave id 0..7 = panel id
    const int r15  = lane & 15;
    const int g    = lane >> 4;         // 0..3
    const float2* row = reinterpret_cast<const float2*>(outs + (size_t)b * NPTS);

    // ---- Stage: Zt[n2][n1] = z[128*n1 + n2] transposed (coalesced global)
    #pragma unroll
    for (int it = 0; it < MPTS / NTHR; ++it) {
        int m = tid + it * NTHR;
        float2 v = row[m];
        bufA[(m & 127) * LD + (m >> 7)] = __floats2half2_rn(v.x, v.y);
    }

    // ---- F fragments for this wave's panel: F[16w+r15][32kc+8g+j].
    // Serve step1 A-side (row=k1) and step3 B-side (col=k2, F symmetric).
    h8 fr[4], fi[4];
    #pragma unroll
    for (int kc = 0; kc < 4; ++kc)
        make_F(16 * w + r15, 32 * kc + 8 * g, fr[kc], fi[kc]);
    __syncthreads();

    // ---- Step 1: Y(panel w) = F * Z; twiddle; PACK PANEL INTO REGISTERS.
    __half2 bm[8][4];                   // 32 VGPR, statically indexed
    #pragma unroll
    for (int n0 = 0; n0 < 8; ++n0) {
        f4 accr = {0.f, 0.f, 0.f, 0.f}, acci = {0.f, 0.f, 0.f, 0.f};
        #pragma unroll
        for (int kc = 0; kc < 4; ++kc) {
            Frag z = load_frag(&bufA[(16 * n0 + r15) * LD + 32 * kc + 8 * g]);
            h8 fin = -fi[kc];
            accr = MFMA(fr[kc], z.r, accr);     // Yr = Fr Zr - Fi Zi
            accr = MFMA(fin,    z.i, accr);
            acci = MFMA(fr[kc], z.i, acci);     // Yi = Fr Zi + Fi Zr
            acci = MFMA(fi[kc], z.r, acci);
        }
        #pragma unroll
        for (int v = 0; v < 4; ++v) {
            int k1 = 16 * w + 4 * g + v;
            int n2 = 16 * n0 + r15;
            int e  = (k1 * n2) & 16383;
            float ang = -3.834951969714103e-4f * (float)e;  // -2pi/16384
            float s, c;
            __sincosf(ang, &s, &c);
            bm[n0][v] = __floats2half2_rn(accr[v] * c - acci[v] * s,
                                          accr[v] * s + acci[v] * c);
        }
    }
    __syncthreads();    // all Zt reads complete

    // ---- Overlay-write Bm[k1][n2] (wave w owns rows 16w..16w+15)
    #pragma unroll
    for (int n0 = 0; n0 < 8; ++n0)
        #pragma unroll
        for (int v = 0; v < 4; ++v)
            bufA[(16 * w + 4 * g + v) * LD + 16 * n0 + r15] = bm[n0][v];
    __syncthreads();

    // ---- Step 3: X = Bm * F (col panel w); pack panel into registers.
    __half2 ct[8][4];                   // reuses bm's registers (bm dead)
    #pragma unroll
    for (int m0 = 0; m0 < 8; ++m0) {
        f4 accr = {0.f, 0.f, 0.f, 0.f}, acci = {0.f, 0.f, 0.f, 0.f};
        #pragma unroll
        for (int kc = 0; kc < 4; ++kc) {
            Frag a = load_frag(&bufA[(16 * m0 + r15) * LD + 32 * kc + 8 * g]);
            h8 ain = -a.i;
            accr = MFMA(a.r, fr[kc], accr);     // Xr = Br Fr - Bi Fi
            accr = MFMA(ain, fi[kc], accr);
            acci = MFMA(a.r, fi[kc], acci);     // Xi = Br Fi + Bi Fr
            acci = MFMA(a.i, fr[kc], acci);
        }
        #pragma unroll
        for (int v = 0; v < 4; ++v)
            ct[m0][v] = __floats2half2_rn(accr[v], acci[v]);
    }
    __syncthreads();    // all Bm reads complete

    // ---- Overlay-write Ct[k2][k1] (wave w owns rows k2 = 16w..16w+15)
    #pragma unroll
    for (int m0 = 0; m0 < 8; ++m0)
        #pragma unroll
        for (int v = 0; v < 4; ++v)
            bufA[(16 * w + r15) * LD + 16 * m0 + 4 * g + v] = ct[m0][v];
    __syncthreads();

    // ---- Band power sum [MIN_IDX, MAX_IDX): direct k indexing, coalesced.
    float local = 0.0f;
    for (int k = MIN_IDX + tid; k < MAX_IDX; k += NTHR)
        local += bin_power2(bufA, k);

    for (int off = 32; off; off >>= 1) local += __shfl_down(local, off);
    if ((tid & 63) == 0) red[w] = local;
    __syncthreads();

    if (tid == 0) {
        float S = 0.0f;
        #pragma unroll
        for (int q = 0; q < NTHR / 64; ++q) S += red[q];

        // ref_idx: argmin_k |f[k]-t|, f[k] = k*(10/16384) exact in fp32.
        float tgt = targets[b];
        double kd = (double)tgt * (16384.0 / 10.0);
        int k0 = (int)kd;                       // t>0 so trunc == floor
        const float stepf = 10.0f / 16384.0f;   // exactly representable
        float f0 = (float)k0 * stepf;           // exact products (<=24b)
        float f1 = (float)(k0 + 1) * stepf;
        float d0 = fabsf(f0 - tgt);
        float d1 = fabsf(f1 - tgt);
        int rr = (d0 <= d1) ? k0 : (k0 + 1);

        float pm1 = bin_power2(bufA, rr - 1);
        float p0  = bin_power2(bufA, rr);
        float pp1 = bin_power2(bufA, rr + 1);
        float other_avg = (S - pm1 - p0 - pp1) * (1.0f / DENOMF);
        row_loss[b] = -10.0f * log10f(p0 / other_avg);
    }
}

__global__ __launch_bounds__(256) void snr_reduce_kernel(
        const float* __restrict__ row_loss, float* __restrict__ out) {
    __shared__ float red[4];
    float s = 0.0f;
    for (int i = threadIdx.x; i < BROWS; i += 256) s += row_loss[i];
    for (int off = 32; off; off >>= 1) s += __shfl_down(s, off);
    if ((threadIdx.x & 63) == 0) red[threadIdx.x >> 6] = s;
    __syncthreads();
    if (threadIdx.x == 0)
        out[0] = (red[0] + red[1] + red[2] + red[3]) * (1.0f / (float)BROWS);
}

extern "C" void kernel_launch(void* const* d_in, const int* in_sizes, int n_in,
                              void* d_out, int out_size, void* d_ws, size_t ws_size,
                              hipStream_t stream) {
    const float* outs    = (const float*)d_in[0];
    const float* targets = (const float*)d_in[1];
    float* ws  = (float*)d_ws;    // 1024 per-row losses
    float* out = (float*)d_out;

    snr_row_kernel<<<BROWS, NTHR, 0, stream>>>(outs, targets, ws);
    snr_reduce_kernel<<<1, 256, 0, stream>>>(ws, out);
}